// Round 13
// baseline (27.727 us; speedup 1.0000x reference)
//
#include <hip/hip_runtime.h>
#include <math.h>

// Canny NMS magnitude extractor — barrier-free register-streaming version.
// 4 independent waves per block; each wave owns a 56-wide x 16-row strip.
// Pipeline (gray -> hblur -> vblur -> sobel/mag/flags -> NMS) in rotating
// named registers; horizontal stencils via ds_bpermute. No LDS, no barriers.
// R13 == R11 byte-for-byte (best passing: 27.7us). R12 (unroll4 + 3-deep
// prefetch) diverged post-timing with no identifiable purity violation;
// reverting to the known-good configuration to test reproducibility.
// x: [16,3,512,512] f32 -> out: [16,3,512,512] f32

#define HH 512
#define WW 512
#define CHX (HH * WW)
#define TH 16            // strip height (output rows per wave)
#define NSX 10           // x-strips (56 cols each)
#define NSY (HH / TH)    // 32 y-strips

__device__ __forceinline__ int reflect_i(int i, int n) {
    if (i < 0) i = -i;
    if (i >= n) i = 2 * n - 2 - i;
    return i;
}

__device__ __forceinline__ float bperm(int byteaddr, float v) {
    return __int_as_float(__builtin_amdgcn_ds_bpermute(byteaddr, __float_as_int(v)));
}

__global__ __launch_bounds__(256, 5)
void canny_stream_kernel(const float* __restrict__ in, float* __restrict__ out) {
    const int lane = threadIdx.x & 63;
    const int sid  = blockIdx.x * 4 + (threadIdx.x >> 6);   // strip id, 0..5119
    const int sx = sid % NSX;
    const int r1 = sid / NSX;
    const int sy = r1 & (NSY - 1);
    const int b  = r1 >> 5;                 // log2(NSY)=5
    const int ty0 = sy * TH;
    const int x   = sx * 56 - 4 + lane;     // lane's column (outputs on lanes 4..59)

    // Gaussian weights exactly as reference (f32 expf, f32 left-to-right sum)
    float g1_0, g1_1, g1_2, g1_3, g1_4;
    {
        float e0 = expf(-2.0f), e1 = expf(-0.5f);
        float s = e0 + e1 + 1.0f + e1 + e0;
        g1_0 = e0 / s; g1_1 = e1 / s; g1_2 = 1.0f / s; g1_3 = e1 / s; g1_4 = e0 / s;
    }

    const float* ldb = in + (size_t)b * 3 * CHX + reflect_i(x, WW);  // column base
    const int xs_ = min(max(x, 0), WW - 1);
    float* ob = out + (size_t)b * 3 * CHX + xs_;                     // safe column base

    // bpermute byte addresses (per-wave local: lane index only)
    const int aL2 = 4 * (lane - 2), aL1 = 4 * (lane - 1);
    const int aR1 = 4 * (lane + 1), aR2 = 4 * (lane + 2);
    const int aSL = 4 * ((x == 0)      ? lane : lane - 1);  // sobel replicate-x left
    const int aSR = 4 * ((x == WW - 1) ? lane : lane + 1);  // sobel replicate-x right
    const bool do_store = (lane >= 4) && (lane <= 59) && (x < WW);
    const bool xin = (x >= 0) && (x < WW);                  // hoisted x-validity

    // rotating pipeline state (all named scalars -> registers)
    float h0 = 0, h1 = 0, h2 = 0, h3 = 0, h4 = 0;                   // hblur rows t-5..t-1
    float bA = 0, bB = 0, bC = 0, bD = 0;                           // blur rows (t-6..t-3)
    float bLA = 0, bLB = 0, bLC = 0, bLD = 0;
    float bRA = 0, bRB = 0, bRC = 0, bRD = 0;
    float mA = 0, mB = 0, mC = 0, mD = 0;                           // mag rows (t-8..t-5)
    float mLA = 0, mLB = 0, mLC = 0, mLD = 0;
    float mRA = 0, mRB = 0, mRC = 0, mRD = 0;
    int   flB = 0, flC = 0, flD = 0;                                // flags (t-7..t-5)

    // pending gray bpermutes (issued at iter t, consumed at iter t+1)
    float pg = 0, pgl2 = 0, pgl1 = 0, pgr1 = 0, pgr2 = 0;

    const int rlo = max(ty0 - 2, 0), rhi = min(ty0 + TH + 1, HH - 1); // blur rows
    const int mlo = ty0 - 1, mhi = ty0 + TH;                          // mag rows

    // 2-deep row prefetch: c* = row t, n* = row t+1; issue t+2 inside loop.
    float c_r, c_g, c_b, n_r, n_g, n_b;
    {
        const float* p0 = ldb + (size_t)reflect_i(ty0 - 4, HH) * WW;
        c_r = p0[0]; c_g = p0[CHX]; c_b = p0[2 * CHX];
        const float* p1 = ldb + (size_t)reflect_i(ty0 - 3, HH) * WW;
        n_r = p1[0]; n_g = p1[CHX]; n_b = p1[2 * CHX];
    }

    #pragma unroll 2
    for (int t = ty0 - 4; t <= ty0 + TH + 6; ++t) {
        // ---- issue row t+2 loads (consumed 2 iterations later) ------------
        float f_r = 0.f, f_g = 0.f, f_b = 0.f;
        if (t + 2 <= ty0 + TH + 3) {
            const float* p = ldb + (size_t)reflect_i(t + 2, HH) * WW;
            f_r = p[0]; f_g = p[CHX]; f_b = p[2 * CHX];
        }

        // ---- rotate pipeline windows (renamed away by unroll) -------------
        bA = bB; bB = bC; bC = bD;
        bLA = bLB; bLB = bLC; bLC = bLD;
        bRA = bRB; bRB = bRC; bRC = bRD;
        mA = mB; mB = mC; mC = mD;
        mLA = mLB; mLB = mLC; mLC = mLD;
        mRA = mRB; mRB = mRC; mRC = mRD;
        flB = flC; flC = flD;
        h0 = h1; h1 = h2; h2 = h3; h3 = h4;

        // ---- NMS + store for row y = t-7 ----------------------------------
        int y = t - 7;
        if (y >= ty0 && y <= ty0 + TH - 1) {
            float mc = mB;
            int f = flB;
            bool fh = (f & 1) != 0, fv = (f & 2) != 0;
            bool fsy = (f & 4) != 0, fsx = (f & 8) != 0;
            float p0 = fv ? mA : (fsx ? mRA : mLA);
            float p1 = fv ? mB : (fsx ? mRB : mLB);
            float p2 = fv ? mC : (fsx ? mRC : mLC);
            float pv = fh ? p1 : (fsy ? p2 : p0);
            float n0 = fv ? mA : (fsx ? mLA : mRA);
            float n1 = fv ? mB : (fsx ? mLB : mRB);
            float n2 = fv ? mC : (fsx ? mLC : mRC);
            float nv = fh ? n1 : (fsy ? n0 : n2);
            float o = (mc > fmaxf(pv, nv)) ? fminf(mc, 1.0f) : 0.0f;
            if (do_store) {
                float* q = ob + (size_t)y * WW;
                q[0] = o; q[CHX] = o; q[2 * CHX] = o;
            }
        }

        // ---- hblur for row t-1, consuming LAST iteration's bpermutes ------
        // (issued a full iteration ago -> lgkm wait is ~free)
        int hb = t - 1;
        if (hb >= ty0 - 4 && hb <= ty0 + TH + 3) {
            h4 = g1_0 * pgl2 + g1_1 * pgl1 + g1_2 * pg + g1_3 * pgr1 + g1_4 * pgr2;
        }

        // ---- vblur row r = t-3 (window h0..h4 = hblur rows r-2..r+2) ------
        int r = t - 3;
        if (r >= rlo && r <= rhi) {
            bD = g1_0 * h0 + g1_1 * h1 + g1_2 * h2 + g1_3 * h3 + g1_4 * h4;
            bLD = bperm(aSL, bD);            // consumed >=1 iter later
            bRD = bperm(aSR, bD);
        }

        // ---- sobel magnitude + flags for row m = t-5 ----------------------
        int m = t - 5;
        if (m >= mlo && m <= mhi) {
            float A, AL, AR, C, CL, CR;
            if (m == 0)      { A = bB; AL = bLB; AR = bRB; }   // replicate-y top
            else             { A = bA; AL = bLA; AR = bRA; }
            if (m == HH - 1) { C = bB; CL = bLB; CR = bRB; }   // replicate-y bottom
            else             { C = bC; CL = bLC; CR = bRC; }
            float BL = bLB, BR = bRB;
            float gx = ((((-AL + AR) - 2.f * BL) + 2.f * BR) - CL) + CR;
            float gy = ((((-AL - 2.f * A) - AR) + CL) + 2.f * C) + CR;
            bool inimg = xin && (m >= 0) && (m < HH);
            mD = inimg ? sqrtf(gx * gx + gy * gy + 1e-6f) : 0.0f;
            float adx = fabsf(gx), ady = fabsf(gy);
            int f = 0;
            f |= (ady <= 0.41421356237309503f * adx) ? 1 : 0;
            f |= (ady >= 2.414213562373095f  * adx) ? 2 : 0;
            f |= (gy >= 0.f) ? 4 : 0;
            f |= (gx >= 0.f) ? 8 : 0;
            flD = f;
            mLD = bperm(aL1, mD);            // consumed >=2 iters later
            mRD = bperm(aR1, mD);
        } else {
            mD = 0.f; mLD = 0.f; mRD = 0.f; flD = 0;
        }

        // ---- gray for row t; ISSUE its bpermutes (consumed next iter) -----
        if (t <= ty0 + TH + 3) {
            float g = c_r * 0.299f + c_g * 0.587f + c_b * 0.114f;
            pgl2 = bperm(aL2, g);
            pgl1 = bperm(aL1, g);
            pgr1 = bperm(aR1, g);
            pgr2 = bperm(aR2, g);
            pg = g;
        }

        // ---- advance prefetch pipeline ------------------------------------
        c_r = n_r; c_g = n_g; c_b = n_b;
        n_r = f_r; n_g = f_g; n_b = f_b;
    }
}

extern "C" void kernel_launch(void* const* d_in, const int* in_sizes, int n_in,
                              void* d_out, int out_size, void* d_ws, size_t ws_size,
                              hipStream_t stream) {
    const float* x = (const float*)d_in[0];
    float* out = (float*)d_out;
    // 10 x-strips * 32 y-strips * 16 images = 5120 strips; 4 waves/block ->
    // 1280 blocks = exactly 5 blocks/CU, 20 waves/CU, zero tail.
    dim3 grid(1280);
    dim3 block(256);
    hipLaunchKernelGGL(canny_stream_kernel, grid, block, 0, stream, x, out);
}

// Round 14
// 25.470 us; speedup vs baseline: 1.0886x; 1.0886x over previous
//
#include <hip/hip_runtime.h>
#include <math.h>

// Canny NMS magnitude extractor — barrier-free register-streaming version.
// 4 independent waves per block; each wave owns a 56-wide x 16-row strip.
// Pipeline (gray -> hblur -> vblur -> sobel/mag/flags -> NMS) in rotating
// named registers; horizontal stencils via ds_bpermute. No LDS, no barriers.
// R14 = R11 + XCD-aware block swizzle (1280 = 8*160, bijective): each XCD
// owns a contiguous y-band of strips so y-halo re-reads hit the local L2.
// x: [16,3,512,512] f32 -> out: [16,3,512,512] f32

#define HH 512
#define WW 512
#define CHX (HH * WW)
#define TH 16            // strip height (output rows per wave)
#define NSX 10           // x-strips (56 cols each)
#define NSY (HH / TH)    // 32 y-strips
#define NXCD 8
#define NBLK 1280        // grid size; NBLK % NXCD == 0 -> simple swizzle bijective

__device__ __forceinline__ int reflect_i(int i, int n) {
    if (i < 0) i = -i;
    if (i >= n) i = 2 * n - 2 - i;
    return i;
}

__device__ __forceinline__ float bperm(int byteaddr, float v) {
    return __int_as_float(__builtin_amdgcn_ds_bpermute(byteaddr, __float_as_int(v)));
}

__global__ __launch_bounds__(256, 5)
void canny_stream_kernel(const float* __restrict__ in, float* __restrict__ out) {
    const int lane = threadIdx.x & 63;
    // XCD-aware swizzle: consecutive-dispatch blocks round-robin across the 8
    // XCDs; remap so each XCD gets a contiguous chunk of 160 block ids
    // (= a contiguous y-band of strips) for L2-local halo-row sharing.
    const int bid  = (int)blockIdx.x;
    const int swz  = (bid % NXCD) * (NBLK / NXCD) + bid / NXCD;
    const int sid  = swz * 4 + (threadIdx.x >> 6);          // strip id, 0..5119
    const int sx = sid % NSX;
    const int r1 = sid / NSX;
    const int sy = r1 & (NSY - 1);
    const int b  = r1 >> 5;                 // log2(NSY)=5
    const int ty0 = sy * TH;
    const int x   = sx * 56 - 4 + lane;     // lane's column (outputs on lanes 4..59)

    // Gaussian weights exactly as reference (f32 expf, f32 left-to-right sum)
    float g1_0, g1_1, g1_2, g1_3, g1_4;
    {
        float e0 = expf(-2.0f), e1 = expf(-0.5f);
        float s = e0 + e1 + 1.0f + e1 + e0;
        g1_0 = e0 / s; g1_1 = e1 / s; g1_2 = 1.0f / s; g1_3 = e1 / s; g1_4 = e0 / s;
    }

    const float* ldb = in + (size_t)b * 3 * CHX + reflect_i(x, WW);  // column base
    const int xs_ = min(max(x, 0), WW - 1);
    float* ob = out + (size_t)b * 3 * CHX + xs_;                     // safe column base

    // bpermute byte addresses (per-wave local: lane index only)
    const int aL2 = 4 * (lane - 2), aL1 = 4 * (lane - 1);
    const int aR1 = 4 * (lane + 1), aR2 = 4 * (lane + 2);
    const int aSL = 4 * ((x == 0)      ? lane : lane - 1);  // sobel replicate-x left
    const int aSR = 4 * ((x == WW - 1) ? lane : lane + 1);  // sobel replicate-x right
    const bool do_store = (lane >= 4) && (lane <= 59) && (x < WW);
    const bool xin = (x >= 0) && (x < WW);                  // hoisted x-validity

    // rotating pipeline state (all named scalars -> registers)
    float h0 = 0, h1 = 0, h2 = 0, h3 = 0, h4 = 0;                   // hblur rows t-5..t-1
    float bA = 0, bB = 0, bC = 0, bD = 0;                           // blur rows (t-6..t-3)
    float bLA = 0, bLB = 0, bLC = 0, bLD = 0;
    float bRA = 0, bRB = 0, bRC = 0, bRD = 0;
    float mA = 0, mB = 0, mC = 0, mD = 0;                           // mag rows (t-8..t-5)
    float mLA = 0, mLB = 0, mLC = 0, mLD = 0;
    float mRA = 0, mRB = 0, mRC = 0, mRD = 0;
    int   flB = 0, flC = 0, flD = 0;                                // flags (t-7..t-5)

    // pending gray bpermutes (issued at iter t, consumed at iter t+1)
    float pg = 0, pgl2 = 0, pgl1 = 0, pgr1 = 0, pgr2 = 0;

    const int rlo = max(ty0 - 2, 0), rhi = min(ty0 + TH + 1, HH - 1); // blur rows
    const int mlo = ty0 - 1, mhi = ty0 + TH;                          // mag rows

    // 2-deep row prefetch: c* = row t, n* = row t+1; issue t+2 inside loop.
    float c_r, c_g, c_b, n_r, n_g, n_b;
    {
        const float* p0 = ldb + (size_t)reflect_i(ty0 - 4, HH) * WW;
        c_r = p0[0]; c_g = p0[CHX]; c_b = p0[2 * CHX];
        const float* p1 = ldb + (size_t)reflect_i(ty0 - 3, HH) * WW;
        n_r = p1[0]; n_g = p1[CHX]; n_b = p1[2 * CHX];
    }

    #pragma unroll 2
    for (int t = ty0 - 4; t <= ty0 + TH + 6; ++t) {
        // ---- issue row t+2 loads (consumed 2 iterations later) ------------
        float f_r = 0.f, f_g = 0.f, f_b = 0.f;
        if (t + 2 <= ty0 + TH + 3) {
            const float* p = ldb + (size_t)reflect_i(t + 2, HH) * WW;
            f_r = p[0]; f_g = p[CHX]; f_b = p[2 * CHX];
        }

        // ---- rotate pipeline windows (renamed away by unroll) -------------
        bA = bB; bB = bC; bC = bD;
        bLA = bLB; bLB = bLC; bLC = bLD;
        bRA = bRB; bRB = bRC; bRC = bRD;
        mA = mB; mB = mC; mC = mD;
        mLA = mLB; mLB = mLC; mLC = mLD;
        mRA = mRB; mRB = mRC; mRC = mRD;
        flB = flC; flC = flD;
        h0 = h1; h1 = h2; h2 = h3; h3 = h4;

        // ---- NMS + store for row y = t-7 ----------------------------------
        int y = t - 7;
        if (y >= ty0 && y <= ty0 + TH - 1) {
            float mc = mB;
            int f = flB;
            bool fh = (f & 1) != 0, fv = (f & 2) != 0;
            bool fsy = (f & 4) != 0, fsx = (f & 8) != 0;
            float p0 = fv ? mA : (fsx ? mRA : mLA);
            float p1 = fv ? mB : (fsx ? mRB : mLB);
            float p2 = fv ? mC : (fsx ? mRC : mLC);
            float pv = fh ? p1 : (fsy ? p2 : p0);
            float n0 = fv ? mA : (fsx ? mLA : mRA);
            float n1 = fv ? mB : (fsx ? mLB : mRB);
            float n2 = fv ? mC : (fsx ? mLC : mRC);
            float nv = fh ? n1 : (fsy ? n0 : n2);
            float o = (mc > fmaxf(pv, nv)) ? fminf(mc, 1.0f) : 0.0f;
            if (do_store) {
                float* q = ob + (size_t)y * WW;
                q[0] = o; q[CHX] = o; q[2 * CHX] = o;
            }
        }

        // ---- hblur for row t-1, consuming LAST iteration's bpermutes ------
        // (issued a full iteration ago -> lgkm wait is ~free)
        int hb = t - 1;
        if (hb >= ty0 - 4 && hb <= ty0 + TH + 3) {
            h4 = g1_0 * pgl2 + g1_1 * pgl1 + g1_2 * pg + g1_3 * pgr1 + g1_4 * pgr2;
        }

        // ---- vblur row r = t-3 (window h0..h4 = hblur rows r-2..r+2) ------
        int r = t - 3;
        if (r >= rlo && r <= rhi) {
            bD = g1_0 * h0 + g1_1 * h1 + g1_2 * h2 + g1_3 * h3 + g1_4 * h4;
            bLD = bperm(aSL, bD);            // consumed >=1 iter later
            bRD = bperm(aSR, bD);
        }

        // ---- sobel magnitude + flags for row m = t-5 ----------------------
        int m = t - 5;
        if (m >= mlo && m <= mhi) {
            float A, AL, AR, C, CL, CR;
            if (m == 0)      { A = bB; AL = bLB; AR = bRB; }   // replicate-y top
            else             { A = bA; AL = bLA; AR = bRA; }
            if (m == HH - 1) { C = bB; CL = bLB; CR = bRB; }   // replicate-y bottom
            else             { C = bC; CL = bLC; CR = bRC; }
            float BL = bLB, BR = bRB;
            float gx = ((((-AL + AR) - 2.f * BL) + 2.f * BR) - CL) + CR;
            float gy = ((((-AL - 2.f * A) - AR) + CL) + 2.f * C) + CR;
            bool inimg = xin && (m >= 0) && (m < HH);
            mD = inimg ? sqrtf(gx * gx + gy * gy + 1e-6f) : 0.0f;
            float adx = fabsf(gx), ady = fabsf(gy);
            int f = 0;
            f |= (ady <= 0.41421356237309503f * adx) ? 1 : 0;
            f |= (ady >= 2.414213562373095f  * adx) ? 2 : 0;
            f |= (gy >= 0.f) ? 4 : 0;
            f |= (gx >= 0.f) ? 8 : 0;
            flD = f;
            mLD = bperm(aL1, mD);            // consumed >=2 iters later
            mRD = bperm(aR1, mD);
        } else {
            mD = 0.f; mLD = 0.f; mRD = 0.f; flD = 0;
        }

        // ---- gray for row t; ISSUE its bpermutes (consumed next iter) -----
        if (t <= ty0 + TH + 3) {
            float g = c_r * 0.299f + c_g * 0.587f + c_b * 0.114f;
            pgl2 = bperm(aL2, g);
            pgl1 = bperm(aL1, g);
            pgr1 = bperm(aR1, g);
            pgr2 = bperm(aR2, g);
            pg = g;
        }

        // ---- advance prefetch pipeline ------------------------------------
        c_r = n_r; c_g = n_g; c_b = n_b;
        n_r = f_r; n_g = f_g; n_b = f_b;
    }
}

extern "C" void kernel_launch(void* const* d_in, const int* in_sizes, int n_in,
                              void* d_out, int out_size, void* d_ws, size_t ws_size,
                              hipStream_t stream) {
    const float* x = (const float*)d_in[0];
    float* out = (float*)d_out;
    // 10 x-strips * 32 y-strips * 16 images = 5120 strips; 4 waves/block ->
    // 1280 blocks = exactly 5 blocks/CU, 20 waves/CU, zero tail.
    dim3 grid(NBLK);
    dim3 block(256);
    hipLaunchKernelGGL(canny_stream_kernel, grid, block, 0, stream, x, out);
}